// Round 10
// baseline (78.646 us; speedup 1.0000x reference)
//
#include <hip/hip_runtime.h>
#include <hip/hip_bf16.h>
#include <stdint.h>

#define NB 2048      // groups
#define D 128
#define NPG 91

typedef __attribute__((ext_vector_type(8))) short short8;
typedef __attribute__((ext_vector_type(4))) float f32x4;
typedef __attribute__((ext_vector_type(16))) float f32x16;

__device__ __forceinline__ unsigned bf16pk(float a, float b) {
  __hip_bfloat162 h2 = __float22bfloat162_rn(make_float2(a, b));
  return *reinterpret_cast<unsigned*>(&h2);   // v_cvt_pk_bf16_f32
}

__device__ __forceinline__ float sigf(float x) {
  float e = __expf(-x);
  return __builtin_amdgcn_rcpf(1.0f + e);     // v_rcp_f32, ~1ulp
}

// K0a: fv[o][b][h] = sum_d feats[last_idx[o][b]][d] * Wv[o][d][h]  + bu[o][h]
__global__ void fv_kernel(const float* __restrict__ feats,
                          const float* __restrict__ Wv,
                          const float* __restrict__ bu,
                          const int* __restrict__ last_idx,
                          float* __restrict__ fv) {
  __shared__ float rows[16][128];
  __shared__ int lidx[16];
  const int o = blockIdx.y;
  const int b0 = blockIdx.x * 16;
  const int t = threadIdx.x;
  if (t < 16) lidx[t] = last_idx[o * NB + b0 + t];
  __syncthreads();
  #pragma unroll
  for (int i = 0; i < 8; ++i) {
    int el = t + i * 256;
    int r = el >> 7, d = el & 127;
    rows[r][d] = feats[(size_t)lidx[r] * D + d];
  }
  __syncthreads();
  const int h = t & 127, half = t >> 7;
  float acc[8];
  #pragma unroll
  for (int j = 0; j < 8; ++j) acc[j] = 0.f;
  const float* wvo = Wv + (size_t)o * D * D + h;
  for (int d0 = 0; d0 < D; d0 += 4) {
    float w0 = wvo[(d0 + 0) * D], w1 = wvo[(d0 + 1) * D];
    float w2 = wvo[(d0 + 2) * D], w3 = wvo[(d0 + 3) * D];
    #pragma unroll
    for (int j = 0; j < 8; ++j) {
      const float4 f = *(const float4*)&rows[half * 8 + j][d0];
      acc[j] += f.x * w0 + f.y * w1 + f.z * w2 + f.w * w3;
    }
  }
  const float bb = bu[o * D + h];
  #pragma unroll
  for (int j = 0; j < 8; ++j)
    fv[((size_t)o * NB + b0 + half * 8 + j) * D + h] = acc[j] + bb;
}

// K0b: pack Wu transposed to bf16 in 32x32x16 A-fragment order (flipped GEMM).
// wupk[((o*8+step)*4 + ht)*64 + row*2 + hi] (uint4)
//   = 8 bf16 of Wu[o][k = step*16 + hi*8 + 0..7][h = ht*32 + row]
__global__ void wut_pack(const float* __restrict__ Wu, uint4* __restrict__ wupk) {
  const int o = blockIdx.x >> 3, step = blockIdx.x & 7;
  const int t = threadIdx.x;          // 256 threads: ht(2b) row(5b) hi(1b)
  const int ht = t >> 6, rh = t & 63;
  const int row = rh >> 1, hi = rh & 1;
  const int k0 = step * 16 + hi * 8;
  const float* src = Wu + (size_t)o * D * D + (size_t)k0 * D + ht * 32 + row;
  uint4 pk;
  pk.x = bf16pk(src[0 * D], src[1 * D]);
  pk.y = bf16pk(src[2 * D], src[3 * D]);
  pk.z = bf16pk(src[4 * D], src[5 * D]);
  pk.w = bf16pk(src[6 * D], src[7 * D]);
  wupk[(size_t)blockIdx.x * 256 + ht * 64 + row * 2 + hi] = pk;
}

// K1: one block per group, 384 threads / 6 waves. Flipped 32x32x16 MFMA:
// 12 output tiles per order (4 h-tiles x 3 node-tiles), wave w does tiles
// {2w, 2w+1}. acc = 16 AGPR; A from L2 (wupk), B from LDS feats (swizzled).
// 32.25 KB LDS -> 5 blocks/CU x 6 waves = 30 waves/CU.
__global__ __launch_bounds__(384, 6) void sihg_main(
    const float* __restrict__ feats,
    const uint4* __restrict__ wupk,
    const float* __restrict__ We,
    const float* __restrict__ fvb,
    float* __restrict__ out) {
  __shared__ __align__(16) char lds[32256];
  constexpr int FE_OFF  = 0;      // 24576: feats bf16 [96]x256B swizzled; later alpha@0, part@2048
  constexpr int BFV_OFF = 24576;  // 1536: f32[3][128] fv+bu
  constexpr int WEL_OFF = 26112;  // 1536: f32[3][128]
  constexpr int EP_OFF  = 27648;  // 4608: f32[4][3][96] e-partials per h-tile

  const int t = threadIdx.x;
  const int b = blockIdx.x;
  const int w = t >> 6;       // wave 0..5
  const int l = t & 63;
  const int l31 = l & 31;
  const int hi = l >> 5;

  float* bfvp = (float*)(lds + BFV_OFF);
  float* wel = (float*)(lds + WEL_OFF);
  float (*ep)[3][96] = (float (*)[3][96])(lds + EP_OFF);

  const float* fbase = feats + (size_t)b * NPG * D;

  // ---- stage feats -> LDS bf16 swizzled (rows 91..95 zeroed); bfv; wel
  #pragma unroll 1
  for (int i = 0; i < 4; ++i) {
    int c = t + i * 384;              // 1536 chunks of 8 bf16
    int r = c >> 4, d0 = (c & 15) * 8;
    uint4 pk4;
    if (r < NPG) {
      const float* src = fbase + r * D + d0;
      float4 f0 = *(const float4*)(src);
      float4 f1 = *(const float4*)(src + 4);
      pk4.x = bf16pk(f0.x, f0.y);
      pk4.y = bf16pk(f0.z, f0.w);
      pk4.z = bf16pk(f1.x, f1.y);
      pk4.w = bf16pk(f1.z, f1.w);
    } else {
      pk4.x = 0u; pk4.y = 0u; pk4.z = 0u; pk4.w = 0u;
    }
    int off = r * 256 + ((d0 * 2) ^ ((r & 7) << 4));
    *(uint4*)(lds + FE_OFF + off) = pk4;
  }
  bfvp[t] = fvb[((size_t)(t >> 7) * NB + b) * D + (t & 127)];
  wel[t] = We[t];
  __syncthreads();

  // ---- 3 orders x 2 tiles: flipped 32x32x16 GEMM + fused epilogue, no barriers
  #pragma unroll 1
  for (int o = 0; o < 3; ++o) {
    #pragma unroll 1
    for (int tt = 0; tt < 2; ++tt) {
      const int tile = w * 2 + tt;    // 0..11
      const int ht = tile & 3;        // h-tile 0..3
      const int nt = tile >> 2;       // node-tile 0..2
      f32x16 acc = {};

      const int brow = nt * 32 + l31;
      const char* bbase = lds + FE_OFF + brow * 256;
      const int swz = (brow & 7) << 4;
      const uint4* abase = wupk + (size_t)(o * 8 * 4 + ht) * 64 + l31 * 2 + hi;

      #pragma unroll 2
      for (int step = 0; step < 8; ++step) {
        uint4 au = abase[(size_t)step * 256];   // ((o*8+step)*4+ht)*64 stride
        short8 av = *reinterpret_cast<short8*>(&au);
        short8 bv = *(const short8*)(bbase + ((step * 32 + hi * 16) ^ swz));
        acc = __builtin_amdgcn_mfma_f32_32x32x16_bf16(av, bv, acc, 0, 0, 0);
      }
      // epilogue: col n = nt*32 + l31; h = ht*32 + j*8 + hi*4 + r  (reg = j*4+r)
      float e = 0.f;
      #pragma unroll
      for (int j = 0; j < 4; ++j) {
        f32x4 bb = *(const f32x4*)&bfvp[o * 128 + ht * 32 + j * 8 + hi * 4];
        f32x4 ww = *(const f32x4*)&wel[o * 128 + ht * 32 + j * 8 + hi * 4];
        e += sigf(acc[j * 4 + 0] + bb[0]) * ww[0];
        e += sigf(acc[j * 4 + 1] + bb[1]) * ww[1];
        e += sigf(acc[j * 4 + 2] + bb[2]) * ww[2];
        e += sigf(acc[j * 4 + 3] + bb[3]) * ww[3];
      }
      e += __shfl_xor(e, 32);
      if (l < 32) ep[ht][o][nt * 32 + l] = e;
    }
  }
  __syncthreads();

  // ---- softmax per order (wave o handles order o; rows >= 91 masked)
  float (*alpha)[96] = (float (*)[96])(lds + FE_OFF);   // overlays dead feats
  if (w < 3) {
    const int o = w;
    const int n1 = l, n2 = l + 64;
    float e1 = -1e30f, e2 = -1e30f;
    if (n1 < NPG) e1 = ep[0][o][n1] + ep[1][o][n1] + ep[2][o][n1] + ep[3][o][n1];
    if (n2 < NPG) e2 = ep[0][o][n2] + ep[1][o][n2] + ep[2][o][n2] + ep[3][o][n2];
    float mx = fmaxf(e1, e2);
    #pragma unroll
    for (int m = 1; m < 64; m <<= 1) mx = fmaxf(mx, __shfl_xor(mx, m));
    float x1 = (n1 < NPG) ? __expf(e1 - mx) : 0.f;
    float x2 = (n2 < NPG) ? __expf(e2 - mx) : 0.f;
    float s = x1 + x2;
    #pragma unroll
    for (int m = 1; m < 64; m <<= 1) s += __shfl_xor(s, m);
    float inv = __builtin_amdgcn_rcpf(s);
    if (n1 < NPG) alpha[o][n1] = x1 * inv;
    if (n2 < NPG) alpha[o][n2] = x2 * inv;
  }
  __syncthreads();

  // ---- weighted sum: half-wave hw owns nodes n = hw + 12k; fp32 from global (L2-hot)
  {
    const int hw = t >> 5;              // 0..11
    const int d4 = (t & 31) * 4;
    float a0x = 0.f, a0y = 0.f, a0z = 0.f, a0w = 0.f;
    float a1x = 0.f, a1y = 0.f, a1z = 0.f, a1w = 0.f;
    float a2x = 0.f, a2y = 0.f, a2z = 0.f, a2w = 0.f;
    #pragma unroll 1
    for (int n = hw; n < NPG; n += 12) {
      float4 f = *(const float4*)(fbase + n * D + d4);
      float al0 = alpha[0][n], al1 = alpha[1][n], al2 = alpha[2][n];
      a0x += f.x * al0; a0y += f.y * al0; a0z += f.z * al0; a0w += f.w * al0;
      a1x += f.x * al1; a1y += f.y * al1; a1z += f.z * al1; a1w += f.w * al1;
      a2x += f.x * al2; a2y += f.y * al2; a2z += f.z * al2; a2w += f.w * al2;
    }
    // fold the two half-waves of this wave
    a0x += __shfl_xor(a0x, 32); a0y += __shfl_xor(a0y, 32);
    a0z += __shfl_xor(a0z, 32); a0w += __shfl_xor(a0w, 32);
    a1x += __shfl_xor(a1x, 32); a1y += __shfl_xor(a1y, 32);
    a1z += __shfl_xor(a1z, 32); a1w += __shfl_xor(a1w, 32);
    a2x += __shfl_xor(a2x, 32); a2y += __shfl_xor(a2y, 32);
    a2z += __shfl_xor(a2z, 32); a2w += __shfl_xor(a2w, 32);
    float* part = (float*)(lds + FE_OFF + 2048);   // [6][384] f32 (after alpha)
    if (l < 32) {
      float4 s0 = {a0x, a0y, a0z, a0w};
      float4 s1 = {a1x, a1y, a1z, a1w};
      float4 s2 = {a2x, a2y, a2z, a2w};
      *(float4*)&part[w * 384 + 0 * 128 + d4] = s0;
      *(float4*)&part[w * 384 + 1 * 128 + d4] = s1;
      *(float4*)&part[w * 384 + 2 * 128 + d4] = s2;
    }
  }
  __syncthreads();
  {
    const float* part = (const float*)(lds + FE_OFF + 2048);
    float s = 0.f;
    #pragma unroll
    for (int j = 0; j < 6; ++j) s += part[j * 384 + t];
    out[(size_t)b * 384 + t] = s;
  }
}

extern "C" void kernel_launch(void* const* d_in, const int* in_sizes, int n_in,
                              void* d_out, int out_size, void* d_ws, size_t ws_size,
                              hipStream_t stream) {
  const float* feats    = (const float*)d_in[0];
  const float* Wu       = (const float*)d_in[1];
  const float* bu       = (const float*)d_in[2];
  const float* Wv       = (const float*)d_in[3];
  const float* We       = (const float*)d_in[4];
  const int*   last_idx = (const int*)d_in[6];
  float* out = (float*)d_out;
  float* fvb  = (float*)d_ws;                              // 3*2048*128 f32 = 3 MB
  uint4* wupk = (uint4*)((char*)d_ws + 3 * NB * D * 4);    // 96 KB

  dim3 g0(128, 3);
  fv_kernel<<<g0, 256, 0, stream>>>(feats, Wv, bu, last_idx, fvb);
  wut_pack<<<24, 256, 0, stream>>>(Wu, wupk);
  sihg_main<<<NB, 384, 0, stream>>>(feats, wupk, We, fvb, out);
}

// Round 11
// 65.229 us; speedup vs baseline: 1.2057x; 1.2057x over previous
//
#include <hip/hip_runtime.h>
#include <hip/hip_bf16.h>
#include <stdint.h>

#define NB 2048      // groups
#define D 128
#define NPG 91

typedef __attribute__((ext_vector_type(8))) short short8;
typedef __attribute__((ext_vector_type(4))) float f32x4;

__device__ __forceinline__ unsigned bf16pk(float a, float b) {
  __hip_bfloat162 h2 = __float22bfloat162_rn(make_float2(a, b));
  return *reinterpret_cast<unsigned*>(&h2);   // v_cvt_pk_bf16_f32
}

__device__ __forceinline__ float sigf(float x) {
  float e = __expf(-x);
  return __builtin_amdgcn_rcpf(1.0f + e);     // v_rcp_f32, ~1ulp
}

// K0: pack Wu (units 0..11) and Wv (units 12..23) transposed to bf16 in MFMA
// A-fragment order (flipped GEMM):
// wpk[u*512 + row*4 + g] (uint4) = 8 bf16 of W[o][kk*32+g*8 + 0..7][row],
// u = o*4+kk (Wu) or 12 + o*4+kk (Wv).
__global__ void w_pack(const float* __restrict__ Wu,
                       const float* __restrict__ Wv,
                       uint4* __restrict__ wpk) {
  const int u = blockIdx.x;
  const float* W = (u < 12) ? Wu : Wv;
  const int uu = (u < 12) ? u : u - 12;
  const int o = uu >> 2, kk = uu & 3;
  const int t = threadIdx.x;
  #pragma unroll
  for (int i = 0; i < 2; ++i) {
    int idx = i * 256 + t;              // 0..511
    int row = idx >> 2, g = idx & 3;
    const float* src = W + (size_t)o * D * D + (kk * 32 + g * 8) * D + row;
    uint4 pk;
    pk.x = bf16pk(src[0 * D], src[1 * D]);
    pk.y = bf16pk(src[2 * D], src[3 * D]);
    pk.z = bf16pk(src[4 * D], src[5 * D]);
    pk.w = bf16pk(src[6 * D], src[7 * D]);
    wpk[(size_t)u * 512 + idx] = pk;
  }
}

// K1: one block per group, 512 threads / 8 waves (R9 geometry).
// Wave q owns h-tile q (16 h). Per order: fused fv mini-GEMM (B = the
// group's own last-row {49,74,90}, A = WvT) -> bias LDS -> barrier ->
// main flipped GEMM (2 node-halves x acc[3]) + fused sigmoid/We epilogue.
__global__ __launch_bounds__(512, 8) void sihg_main(
    const float* __restrict__ feats,
    const uint4* __restrict__ wpk,
    const float* __restrict__ bu,
    const float* __restrict__ We,
    float* __restrict__ out) {
  __shared__ __align__(16) char lds[38528];
  constexpr int FE_OFF  = 0;      // 24576: feats bf16 [96]x256B swizzled; later part[8][384]
  constexpr int BFV_OFF = 24576;  // 512:  f32[128] fv+bu for current order
  constexpr int BUL_OFF = 25088;  // 1536: f32[3][128] bu
  constexpr int WEL_OFF = 26624;  // 1536: f32[3][128] We
  constexpr int EP_OFF  = 28160;  // 9216: f32[8][3][96] e-partials per h-tile wave
  constexpr int AL_OFF  = 37376;  // 1152: f32[3][96] alpha

  const int t = threadIdx.x;
  const int b = blockIdx.x;
  const int q = t >> 6;       // wave = h-tile 0..7
  const int l = t & 63;
  const int g = l >> 4;
  const int lm = l & 15;

  float* bfvp = (float*)(lds + BFV_OFF);
  float* bul = (float*)(lds + BUL_OFF);
  float* wel = (float*)(lds + WEL_OFF);
  float (*ep)[3][96] = (float (*)[3][96])(lds + EP_OFF);
  float (*alpha)[96] = (float (*)[96])(lds + AL_OFF);

  const float* fbase = feats + (size_t)b * NPG * D;

  // ---- stage feats -> LDS bf16 swizzled (rows 91..95 zeroed); bu; We
  #pragma unroll 1
  for (int i = 0; i < 3; ++i) {
    int c = t + i * 512;              // 1536 chunks of 8 bf16
    int r = c >> 4, d0 = (c & 15) * 8;
    uint4 pk4;
    if (r < NPG) {
      const float* src = fbase + r * D + d0;
      float4 f0 = *(const float4*)(src);
      float4 f1 = *(const float4*)(src + 4);
      pk4.x = bf16pk(f0.x, f0.y);
      pk4.y = bf16pk(f0.z, f0.w);
      pk4.z = bf16pk(f1.x, f1.y);
      pk4.w = bf16pk(f1.z, f1.w);
    } else {
      pk4.x = 0u; pk4.y = 0u; pk4.z = 0u; pk4.w = 0u;
    }
    int off = r * 256 + ((d0 * 2) ^ ((r & 7) << 4));
    *(uint4*)(lds + FE_OFF + off) = pk4;
  }
  if (t < 384) {
    bul[t] = bu[t];
    wel[t] = We[t];
  }
  __syncthreads();

  const int LROW[3] = {49, 74, 90};   // last node of each order within the group

  // ---- 3 orders: fv mini-GEMM -> bias; main GEMM + fused epilogue
  #pragma unroll 1
  for (int o = 0; o < 3; ++o) {
    // fv: A = WvT frags, B = uniform last-row of this block's feats tile.
    {
      const int frow = LROW[o];
      const int fswz = (frow & 7) << 4;
      f32x4 z = {0.f, 0.f, 0.f, 0.f};
      #pragma unroll
      for (int kk = 0; kk < 4; ++kk) {
        short8 av = *(const short8*)&wpk[(size_t)(12 + o * 4 + kk) * 512 + (q * 16 + lm) * 4 + g];
        short8 bv = *(const short8*)(lds + FE_OFF + frow * 256 + ((kk * 64 + g * 16) ^ fswz));
        z = __builtin_amdgcn_mfma_f32_16x16x32_bf16(av, bv, z, 0, 0, 0);
      }
      // every col identical; col 0 lanes write bias = fv + bu
      if (lm == 0) {
        #pragma unroll
        for (int r = 0; r < 4; ++r)
          bfvp[q * 16 + g * 4 + r] = z[r] + bul[o * 128 + q * 16 + g * 4 + r];
      }
    }
    __syncthreads();                  // bias visible to all waves

    // A-fragments for this order (shared across both node-halves)
    short8 a[4];
    #pragma unroll
    for (int kk = 0; kk < 4; ++kk)
      a[kk] = *(const short8*)&wpk[(size_t)(o * 4 + kk) * 512 + (q * 16 + lm) * 4 + g];

    #pragma unroll 1
    for (int nh = 0; nh < 2; ++nh) {
      f32x4 acc[3];
      #pragma unroll
      for (int j = 0; j < 3; ++j) acc[j] = (f32x4){0.f, 0.f, 0.f, 0.f};

      #pragma unroll
      for (int kk = 0; kk < 4; ++kk) {
        const int cb = kk * 64 + g * 16;
        #pragma unroll
        for (int j = 0; j < 3; ++j) {
          const int nt = nh * 3 + j;
          short8 bfr = *(const short8*)(lds + FE_OFF + (nt * 16 + lm) * 256 + (cb ^ ((lm & 7) << 4)));
          acc[j] = __builtin_amdgcn_mfma_f32_16x16x32_bf16(a[kk], bfr, acc[j], 0, 0, 0);
        }
      }
      // epilogue: h = q*16 + g*4 + r  (C/D row = g*4+r, col = lm)
      const float* bbp = &bfvp[q * 16 + g * 4];
      const float* wwp = &wel[o * 128 + q * 16 + g * 4];
      #pragma unroll
      for (int j = 0; j < 3; ++j) {
        float e = 0.f;
        #pragma unroll
        for (int r = 0; r < 4; ++r)
          e += sigf(acc[j][r] + bbp[r]) * wwp[r];
        e += __shfl_xor(e, 16);
        e += __shfl_xor(e, 32);
        if (l < 16) ep[q][o][(nh * 3 + j) * 16 + l] = e;
      }
    }
    if (o < 2) __syncthreads();       // epilogue bias reads done before next fv write
  }
  __syncthreads();

  // ---- softmax per order (wave o handles order o; rows >= 91 masked)
  if (q < 3) {
    const int o = q;
    const int n1 = l, n2 = l + 64;
    float e1 = -1e30f, e2 = -1e30f;
    if (n1 < NPG) {
      e1 = 0.f;
      #pragma unroll
      for (int j = 0; j < 8; ++j) e1 += ep[j][o][n1];
    }
    if (n2 < NPG) {
      e2 = 0.f;
      #pragma unroll
      for (int j = 0; j < 8; ++j) e2 += ep[j][o][n2];
    }
    float mx = fmaxf(e1, e2);
    #pragma unroll
    for (int m = 1; m < 64; m <<= 1) mx = fmaxf(mx, __shfl_xor(mx, m));
    float x1 = (n1 < NPG) ? __expf(e1 - mx) : 0.f;
    float x2 = (n2 < NPG) ? __expf(e2 - mx) : 0.f;
    float s = x1 + x2;
    #pragma unroll
    for (int m = 1; m < 64; m <<= 1) s += __shfl_xor(s, m);
    float inv = __builtin_amdgcn_rcpf(s);
    if (n1 < NPG) alpha[o][n1] = x1 * inv;
    if (n2 < NPG) alpha[o][n2] = x2 * inv;
  }
  __syncthreads();

  // ---- weighted sum: half-wave hw owns nodes n = hw + 16k; fp32 from global (L2-hot)
  {
    const int hw = t >> 5;              // 0..15
    const int d4 = (t & 31) * 4;
    float a0x = 0.f, a0y = 0.f, a0z = 0.f, a0w = 0.f;
    float a1x = 0.f, a1y = 0.f, a1z = 0.f, a1w = 0.f;
    float a2x = 0.f, a2y = 0.f, a2z = 0.f, a2w = 0.f;
    #pragma unroll 1
    for (int n = hw; n < NPG; n += 16) {
      float4 f = *(const float4*)(fbase + n * D + d4);
      float al0 = alpha[0][n], al1 = alpha[1][n], al2 = alpha[2][n];
      a0x += f.x * al0; a0y += f.y * al0; a0z += f.z * al0; a0w += f.w * al0;
      a1x += f.x * al1; a1y += f.y * al1; a1z += f.z * al1; a1w += f.w * al1;
      a2x += f.x * al2; a2y += f.y * al2; a2z += f.z * al2; a2w += f.w * al2;
    }
    // fold the two half-waves of this wave
    a0x += __shfl_xor(a0x, 32); a0y += __shfl_xor(a0y, 32);
    a0z += __shfl_xor(a0z, 32); a0w += __shfl_xor(a0w, 32);
    a1x += __shfl_xor(a1x, 32); a1y += __shfl_xor(a1y, 32);
    a1z += __shfl_xor(a1z, 32); a1w += __shfl_xor(a1w, 32);
    a2x += __shfl_xor(a2x, 32); a2y += __shfl_xor(a2y, 32);
    a2z += __shfl_xor(a2z, 32); a2w += __shfl_xor(a2w, 32);
    float* part = (float*)(lds + FE_OFF);   // [8][384] f32, overlays dead feats tile
    if (l < 32) {
      float4 s0 = {a0x, a0y, a0z, a0w};
      float4 s1 = {a1x, a1y, a1z, a1w};
      float4 s2 = {a2x, a2y, a2z, a2w};
      *(float4*)&part[q * 384 + 0 * 128 + d4] = s0;
      *(float4*)&part[q * 384 + 1 * 128 + d4] = s1;
      *(float4*)&part[q * 384 + 2 * 128 + d4] = s2;
    }
  }
  __syncthreads();
  if (t < 384) {
    const float* part = (const float*)(lds + FE_OFF);
    float s = 0.f;
    #pragma unroll
    for (int j = 0; j < 8; ++j) s += part[j * 384 + t];
    out[(size_t)b * 384 + t] = s;
  }
}

extern "C" void kernel_launch(void* const* d_in, const int* in_sizes, int n_in,
                              void* d_out, int out_size, void* d_ws, size_t ws_size,
                              hipStream_t stream) {
  const float* feats = (const float*)d_in[0];
  const float* Wu    = (const float*)d_in[1];
  const float* bu    = (const float*)d_in[2];
  const float* Wv    = (const float*)d_in[3];
  const float* We    = (const float*)d_in[4];
  float* out = (float*)d_out;
  uint4* wpk = (uint4*)d_ws;          // 24*512*16 = 192 KB

  w_pack<<<24, 256, 0, stream>>>(Wu, Wv, wpk);
  sihg_main<<<NB, 512, 0, stream>>>(feats, wpk, bu, We, out);
}